// Round 3
// baseline (423.220 us; speedup 1.0000x reference)
//
#include <hip/hip_runtime.h>
#include <math.h>

#define NTOK 8192
#define NPG  512
#define MNEI 32
#define DM   256
#define DE   128
#define NH   8

// workspace offsets (in floats)
#define OFF_WV    0u          // 256*256  (UNUSED now — tokprep reads Wqkv directly)
#define OFF_WQAK  65536u      // 16*256   [c][k] qa/ka transposed
#define OFF_BCAT  69632u      // 16 (cols 0..7 qa bias + edge-LN const fold, 8..15 ka bias)
#define OFF_WEF   69904u      // 8*128  [h][r]  wg = wef * ln_e_g  (LN gain folded)
#define OFF_FLAG  70936u      // 1 int
#define OFF_QA    70944u      // 8192*8
#define OFF_KA    136480u     // 8192*8
#define OFF_GATE  202016u     // 8192
#define OFF_VW    210208u     // 8192*256
#define OFF_PROJ  2307360u    // 8192*3
#define OFF_VMAT  2331936u    // 16*9
#define OFF_CEN   2332080u    // 16*3
#define OFF_HCAT  2332128u    // 8192*384

#define OUT_GEO_OFF 2097152   // 8192*256

__device__ __forceinline__ void fma4x4(const float4 a, const float4 w, float4* acc) {
    acc[0].x += a.x*w.x; acc[0].y += a.x*w.y; acc[0].z += a.x*w.z; acc[0].w += a.x*w.w;
    acc[1].x += a.y*w.x; acc[1].y += a.y*w.y; acc[1].z += a.y*w.z; acc[1].w += a.y*w.w;
    acc[2].x += a.z*w.x; acc[2].y += a.z*w.y; acc[2].z += a.z*w.z; acc[2].w += a.z*w.w;
    acc[3].x += a.w*w.x; acc[3].y += a.w*w.y; acc[3].z += a.w*w.z; acc[3].w += a.w*w.w;
}

__device__ __forceinline__ float dot4(const float4 a, const float4 b) {
    return a.x*b.x + a.y*b.y + a.z*b.z + a.w*b.w;
}

// ---------------- Kernel 1: merged preprocessing --------------------------
// block 0: mask layout detect; block 1: BCAT[0..15] (parallel fold);
// blocks 2..17: WQAK (c = b-2); blocks 18..21: WEF; blocks 22..37: per-graph
// geometry (center, cov, eigh, proj). All parts independent.
__global__ __launch_bounds__(256) void k_pre(
    const float* __restrict__ Wqkv, const float* __restrict__ bqkv,
    const float* __restrict__ Wqkve, const float* __restrict__ bqkve,
    const float* __restrict__ w_attn, const float* __restrict__ w_edge,
    const float* __restrict__ lneg, const float* __restrict__ lneb,
    const int* __restrict__ maskp, const float* __restrict__ geo,
    float* __restrict__ ws)
{
    int t = threadIdx.x;
    int b = blockIdx.x;

    if (b == 0) {
        // ---- mask layout detection ----
        __shared__ int sbad, sflt;
        if (t == 0) { sbad = 0; sflt = 0; }
        __syncthreads();
        int bad = 0, flt = 0;
        for (int i = 0; i < 256; i++) {
            unsigned int w = (unsigned int)maskp[i*256 + t];
            if (w > 1u) bad = 1;
            if (w == 0x3F800000u) flt = 1;
        }
        if (bad) atomicOr(&sbad, 1);
        if (flt) atomicOr(&sflt, 1);
        __syncthreads();
        if (t == 0) {
            int f = sflt ? 2 : (sbad ? 1 : 0);
            ((int*)(ws + OFF_FLAG))[0] = f;
        }
        return;
    }
    if (b == 1) {
        // ---- BCAT[0..15]: qa bias + edge-LN const fold, ka bias ----
        int h = t >> 5, l = t & 31;
        float p = 0.f;
        for (int q = 0; q < 4; q++) {
            int r = l + 32*q;
            float wef = 0.f;
            for (int e = 0; e < 16; e++) wef += Wqkve[r*256 + h*16 + e] * w_edge[e];
            p += lneb[r] * wef;
        }
        for (int m = 16; m >= 1; m >>= 1) p += __shfl_xor(p, m, 32);
        if (l == 0) {
            float s = p;
            for (int d = 0; d < 32; d++) s += bqkv[h*32 + d] * w_attn[d];
            for (int e = 0; e < 16; e++) s += bqkve[h*16 + e] * w_edge[e];
            ws[OFF_BCAT + h] = s;
        }
        if (l == 1) {
            float s = 0.f;
            for (int d = 0; d < 32; d++) s += bqkv[256 + h*32 + d] * w_attn[d];
            ws[OFF_BCAT + 8 + h] = s;
        }
        return;
    }
    if (b < 18) {
        // ---- WQAK: c = b-2, one k per thread ----
        int c = b - 2, k = t;
        int h = c & 7; int off = (c < 8) ? 0 : 256;
        float s = 0.f;
        for (int d = 0; d < 32; d++) s += Wqkv[k*768 + off + h*32 + d] * w_attn[d];
        ws[OFF_WQAK + c*256 + k] = s;
        return;
    }
    if (b < 22) {
        // ---- WEF: wg[h][r] = (Σ_e Wqkve·w_edge) · lneg[r] ----
        int i = (b - 18)*256 + t;
        int h = i >> 7, r = i & 127;
        float s = 0.f;
        for (int e = 0; e < 16; e++) s += Wqkve[r*256 + h*16 + e] * w_edge[e];
        ws[OFF_WEF + i] = s * lneg[r];
        return;
    }

    // ---- per-graph geometry: g = b - 22 ----
    {
        __shared__ float sred[4 * 9];
        __shared__ float sres[9];
        __shared__ float sV[9];
        int g = b - 22;
        int wave = t >> 6, lane = t & 63;
        const float* gp = geo + (size_t)g * NPG * 3;

        float x0[2], y0[2], z0[2];
        float sx = 0.f, sy = 0.f, sz = 0.f;
        for (int i = 0; i < 2; i++) {
            int p = t + 256 * i;
            x0[i] = gp[p*3 + 0]; y0[i] = gp[p*3 + 1]; z0[i] = gp[p*3 + 2];
            sx += x0[i]; sy += y0[i]; sz += z0[i];
        }
        {
            float vals[3] = {sx, sy, sz};
            for (int q = 0; q < 3; q++) {
                float v = vals[q];
                for (int m = 32; m >= 1; m >>= 1) v += __shfl_xor(v, m, 64);
                if (lane == 0) sred[wave*9 + q] = v;
            }
        }
        __syncthreads();
        if (t < 3) {
            float s = 0.f;
            for (int w = 0; w < 4; w++) s += sred[w*9 + t];
            sres[t] = s * (1.0f / 512.0f);
        }
        __syncthreads();
        float cx = sres[0], cy = sres[1], cz = sres[2];

        float c6[6] = {0.f, 0.f, 0.f, 0.f, 0.f, 0.f};
        for (int i = 0; i < 2; i++) {
            float dx = x0[i] - cx, dy = y0[i] - cy, dz = z0[i] - cz;
            c6[0] += dx*dx; c6[1] += dx*dy; c6[2] += dx*dz;
            c6[3] += dy*dy; c6[4] += dy*dz; c6[5] += dz*dz;
        }
        for (int q = 0; q < 6; q++) {
            float v = c6[q];
            for (int m = 32; m >= 1; m >>= 1) v += __shfl_xor(v, m, 64);
            if (lane == 0) sred[wave*9 + q] = v;
        }
        __syncthreads();
        if (t < 6) {
            float s = 0.f;
            for (int w = 0; w < 4; w++) s += sred[w*9 + t];
            sres[t] = s;
        }
        __syncthreads();

        if (t == 0) {
            double a[3][3];
            a[0][0] = sres[0]; a[0][1] = a[1][0] = sres[1]; a[0][2] = a[2][0] = sres[2];
            a[1][1] = sres[3]; a[1][2] = a[2][1] = sres[4]; a[2][2] = sres[5];
            double v[3][3] = {{1,0,0},{0,1,0},{0,0,1}};
            const int ps[3] = {0, 0, 1}, qs[3] = {1, 2, 2};
            for (int sweep = 0; sweep < 10; sweep++) {
                for (int pi = 0; pi < 3; pi++) {
                    int p = ps[pi], q = qs[pi];
                    double apq = a[p][q];
                    if (fabs(apq) < 1e-300) continue;
                    double theta = (a[q][q] - a[p][p]) / (2.0 * apq);
                    double tt = ((theta >= 0.0) ? 1.0 : -1.0) / (fabs(theta) + sqrt(theta*theta + 1.0));
                    double c = 1.0 / sqrt(tt*tt + 1.0), s = tt * c;
                    int k = 3 - p - q;
                    double app = a[p][p], aqq = a[q][q], akp = a[k][p], akq = a[k][q];
                    a[p][p] = app - tt * apq;
                    a[q][q] = aqq + tt * apq;
                    a[p][q] = 0.0; a[q][p] = 0.0;
                    a[k][p] = c*akp - s*akq; a[p][k] = a[k][p];
                    a[k][q] = s*akp + c*akq; a[q][k] = a[k][q];
                    for (int kk = 0; kk < 3; kk++) {
                        double vp = v[kk][p], vq = v[kk][q];
                        v[kk][p] = c*vp - s*vq;
                        v[kk][q] = s*vp + c*vq;
                    }
                }
            }
            for (int r = 0; r < 3; r++)
                for (int c2 = 0; c2 < 3; c2++) {
                    float fv = (float)v[r][c2];
                    sV[r*3 + c2] = fv;
                    ws[OFF_VMAT + g*9 + r*3 + c2] = fv;
                }
            ws[OFF_CEN + g*3 + 0] = cx;
            ws[OFF_CEN + g*3 + 1] = cy;
            ws[OFF_CEN + g*3 + 2] = cz;
        }
        __syncthreads();

        for (int i = 0; i < 2; i++) {
            int p = t + 256 * i;
            float dx = x0[i] - cx, dy = y0[i] - cy, dz = z0[i] - cz;
            for (int c = 0; c < 3; c++) {
                float pr = dx * sV[0*3 + c] + dy * sV[1*3 + c] + dz * sV[2*3 + c];
                ws[OFF_PROJ + (size_t)(g*NPG + p)*3 + c] = pr;
            }
        }
    }
}

// ---------------- Kernel 2: token LN + gate + [qa|ka|v] ---------------------
// v3: v-GEMM rebalanced across ALL 4 waves (thread: 2 tokens x 4 cols,
// full K=256, 2048 FMA) reading Wqkv directly (stride-768 coalesced float4).
// qa/ka afterwards on t<128 (no barrier needed; sln is stable).
__global__ __launch_bounds__(256) void k_tokprep(
    const float* __restrict__ tok, const float* __restrict__ ln_g,
    const float* __restrict__ ln_b, const float* __restrict__ Wgate,
    const float* __restrict__ bgate, const float* __restrict__ Wqkv,
    const float* __restrict__ bqkv, float* __restrict__ ws)
{
    __shared__ __align__(16) float sln[256 * 12];   // [k][8 tokens + pad]
    int t = threadIdx.x;
    int tok0 = blockIdx.x * 8;

    #pragma unroll
    for (int q = 0; q < 8; q++)
        sln[t*12 + q] = tok[(size_t)(tok0 + q) * 256 + t];
    __syncthreads();

    int wave = t >> 6, lane = t & 63;
    for (int rr = 0; rr < 2; rr++) {
        int tt = wave * 2 + rr;
        float s = 0.f, gdot = 0.f;
        float xs[4];
        #pragma unroll
        for (int q = 0; q < 4; q++) {
            int k = lane + 64*q;
            float x = sln[k*12 + tt];
            xs[q] = x; s += x; gdot += x * Wgate[k];
        }
        for (int m = 32; m >= 1; m >>= 1) { s += __shfl_xor(s,m,64); gdot += __shfl_xor(gdot,m,64); }
        float mu = s * (1.0f/256.0f);
        float vs = 0.f;
        #pragma unroll
        for (int q = 0; q < 4; q++) { float d = xs[q]-mu; vs += d*d; }
        for (int m = 32; m >= 1; m >>= 1) vs += __shfl_xor(vs,m,64);
        float rinv = rsqrtf(vs*(1.0f/256.0f)+1e-5f);
        #pragma unroll
        for (int q = 0; q < 4; q++) {
            int k = lane + 64*q;
            sln[k*12 + tt] = (xs[q]-mu)*rinv*ln_g[k] + ln_b[k];
        }
        if (lane == 0) ws[OFF_GATE + tok0 + tt] = 1.0f/(1.0f+expf(-(gdot + bgate[0])));
    }
    __syncthreads();

    // ---- v-GEMM: all waves; thread (i = t>>6 -> tokens 2i,2i+1; j = t&63) ----
    {
        int i = t >> 6, j = t & 63;
        const float* Wc = Wqkv + 512 + 4*j;
        float4 acc0 = make_float4(0.f,0.f,0.f,0.f);
        float4 acc1 = make_float4(0.f,0.f,0.f,0.f);
        #pragma unroll 8
        for (int k = 0; k < 256; k++) {
            float a0 = sln[k*12 + 2*i];
            float a1 = sln[k*12 + 2*i + 1];
            float4 w4 = *(const float4*)&Wc[(size_t)k*768];
            acc0.x += a0*w4.x; acc0.y += a0*w4.y; acc0.z += a0*w4.z; acc0.w += a0*w4.w;
            acc1.x += a1*w4.x; acc1.y += a1*w4.y; acc1.z += a1*w4.z; acc1.w += a1*w4.w;
        }
        float4 b4 = *(const float4*)&bqkv[512 + 4*j];
        int n0 = tok0 + 2*i;
        acc0.x += b4.x; acc0.y += b4.y; acc0.z += b4.z; acc0.w += b4.w;
        acc1.x += b4.x; acc1.y += b4.y; acc1.z += b4.z; acc1.w += b4.w;
        *(float4*)&ws[OFF_VW + (size_t)n0*256 + 4*j]     = acc0;
        *(float4*)&ws[OFF_VW + (size_t)(n0+1)*256 + 4*j] = acc1;
    }

    // ---- qa/ka: t<128 (col = t&15, token tp = t>>4) ----
    if (t < 128) {
        int col = t & 15, tp = t >> 4;
        const float* wq = ws + OFF_WQAK + col*256;
        float acc = 0.f;
        #pragma unroll 8
        for (int k4 = 0; k4 < 64; k4++) {
            float4 w4 = *(const float4*)&wq[4*k4];
            acc += w4.x * sln[(4*k4+0)*12 + tp]
                 + w4.y * sln[(4*k4+1)*12 + tp]
                 + w4.z * sln[(4*k4+2)*12 + tp]
                 + w4.w * sln[(4*k4+3)*12 + tp];
        }
        acc += ws[OFF_BCAT + col];
        int n = tok0 + tp;
        if (col < 8) ws[OFF_QA + n*8 + col] = acc;
        else         ws[OFF_KA + n*8 + (col - 8)] = acc;
    }
}

// ---------------- Kernel 3: fused per-token attention (LN-folded) ----------
// v3: P4 edge-ctx GEMM K-split within 8 consecutive lanes (r = ri*8+ks,
// 3x shfl_xor width-8 reduce) -> bar5 + sec round-trip + P5 pass removed.
// 4 barriers. LDS 22.5 KB.
__global__ __launch_bounds__(256) void k_attn(
    const float* __restrict__ edge, const int* __restrict__ nbr,
    const void* __restrict__ maskp,
    const float* __restrict__ lneg, const float* __restrict__ lneb,
    const float* __restrict__ bqkve, const float* __restrict__ Wqkve,
    const float* __restrict__ Wfa, const float* __restrict__ bfa,
    const float* __restrict__ geo, float* __restrict__ ws, float* __restrict__ out)
{
    __shared__ __align__(16) float se[32 * 132];    // centered edge rows
    __shared__ __align__(16) float uSWE[8 * 132];   // [sub][h][16] wg; sew aliases after logits
    __shared__ __align__(16) float sattn[8 * 36];   // logits -> attn (in place)
    __shared__ float srinv[32];
    __shared__ int   snbr[32];
    __shared__ float sg3[4];

    int t = threadIdx.x;
    int n = blockIdx.x;
    int g = n >> 9;
    int flag = ((const int*)(ws + OFF_FLAG))[0];

    int m = t >> 3, sub = t & 7;

    // ---- P0: direct global->reg row load + small staging ----
    const float4* xp = (const float4*)(edge + (size_t)n * 4096 + m*128 + sub*16);
    float4 x0 = xp[0], x1 = xp[1], x2 = xp[2], x3 = xp[3];
    {
        // wg weights re-laid out sub-major: uSWE[s2*132 + h*16 + c]
        int idx = t * 4;
        int h = idx >> 7, r = idx & 127;
        int s2 = r >> 4, c = r & 15;
        *(float4*)&uSWE[s2*132 + h*16 + c] = *(const float4*)&ws[OFF_WEF + idx];
    }
    if (t < 32) snbr[t] = nbr[n*32 + t];
    __syncthreads();   // bar1

    // ---- P1: row stats + centered-row LDS write + logits from registers ----
    {
        float s = x0.x+x0.y+x0.z+x0.w + x1.x+x1.y+x1.z+x1.w
                + x2.x+x2.y+x2.z+x2.w + x3.x+x3.y+x3.z+x3.w;
        for (int mm = 4; mm >= 1; mm >>= 1) s += __shfl_xor(s, mm, 8);
        float mu = s * (1.0f / 128.0f);
        x0.x-=mu; x0.y-=mu; x0.z-=mu; x0.w-=mu;
        x1.x-=mu; x1.y-=mu; x1.z-=mu; x1.w-=mu;
        x2.x-=mu; x2.y-=mu; x2.z-=mu; x2.w-=mu;
        x3.x-=mu; x3.y-=mu; x3.z-=mu; x3.w-=mu;
        float vs = dot4(x0,x0) + dot4(x1,x1) + dot4(x2,x2) + dot4(x3,x3);
        for (int mm = 4; mm >= 1; mm >>= 1) vs += __shfl_xor(vs, mm, 8);
        float rinv = rsqrtf(vs * (1.0f / 128.0f) + 1e-5f);
        float4* sp = (float4*)&se[m*132 + sub*16];
        sp[0] = x0; sp[1] = x1; sp[2] = x2; sp[3] = x3;
        if (sub == 0) srinv[m] = rinv;

        // logits: dot(wg[h], x - mu) for all h, butterfly over 8 sub-lanes
        float accl[8];
        const float* wb = &uSWE[sub*132];
        #pragma unroll
        for (int h = 0; h < 8; h++) {
            const float4* wp = (const float4*)(wb + h*16);
            accl[h] = dot4(x0,wp[0]) + dot4(x1,wp[1]) + dot4(x2,wp[2]) + dot4(x3,wp[3]);
        }
        #pragma unroll
        for (int st = 1; st < 8; st <<= 1) {
            #pragma unroll
            for (int h = 0; h < 8; h++) accl[h] += __shfl_xor(accl[h], st, 8);
        }
        float myacc = accl[0];
        #pragma unroll
        for (int h = 1; h < 8; h++) myacc = (sub == h) ? accl[h] : myacc;

        int mv;
        if (flag == 1)      mv = (int)((const unsigned char*)maskp)[n*32 + m];
        else if (flag == 2) mv = (((const float*)maskp)[n*32 + m] != 0.0f) ? 1 : 0;
        else                mv = ((const int*)maskp)[n*32 + m];

        float lg = myacc * rinv
                 + ws[OFF_QA + n*8 + sub]
                 + ws[OFF_KA + (size_t)snbr[m]*8 + sub];
        if (!mv) lg = -1e9f;
        sattn[sub*36 + m] = lg;
    }
    __syncthreads();   // bar2

    // ---- P2: softmax over m per h (in place) ----
    {
        int h = t >> 5, m2 = t & 31;
        float x = sattn[h*36 + m2];
        float mx = x;
        for (int mm = 16; mm >= 1; mm >>= 1) mx = fmaxf(mx, __shfl_xor(mx, mm, 32));
        float e = expf(x - mx);
        float sum = e;
        for (int mm = 16; mm >= 1; mm >>= 1) sum += __shfl_xor(sum, mm, 32);
        sattn[h*36 + m2] = e / sum;
    }
    __syncthreads();   // bar3 (uSWE dead -> sew aliases it)

    float* sew = uSWE;

    // ---- P3: wave-specialized: sctx gather | geo | weighted centered rows ----
    int wave = t >> 6;
    if (wave == 0) {
        int c4 = t, h = c4 >> 3;
        const float* vw = ws + OFF_VW;
        float4 acc = make_float4(0.f,0.f,0.f,0.f);
        #pragma unroll 4
        for (int mi = 0; mi < 32; mi++) {
            float a = sattn[h*36 + mi];
            int row = snbr[mi];
            float4 v4 = *(const float4*)&vw[(size_t)row*256 + 4*c4];
            acc.x += a*v4.x; acc.y += a*v4.y; acc.z += a*v4.z; acc.w += a*v4.w;
        }
        *(float4*)&ws[OFF_HCAT + (size_t)n*384 + 4*c4] = acc;
    } else if (wave == 1) {
        int lm = t - 64;
        if (lm < 32) {
            float wmv = 0.f;
            #pragma unroll
            for (int h2 = 0; h2 < 8; h2++) wmv += Wfa[h2] * sattn[h2*36 + lm];
            int row = snbr[lm];
            const float* pp = ws + OFF_PROJ + (size_t)row*3;
            float q0 = wmv * pp[0], q1 = wmv * pp[1], q2 = wmv * pp[2];
            for (int st = 16; st >= 1; st >>= 1) {
                q0 += __shfl_xor(q0, st, 32);
                q1 += __shfl_xor(q1, st, 32);
                q2 += __shfl_xor(q2, st, 32);
            }
            if (lm < 3) {
                float sd = (lm == 0) ? q0 : (lm == 1) ? q1 : q2;
                float bb = bfa[0];
                float p1 = sd + bb, p2 = -sd + bb;
                float s1v = p1 / (1.0f + expf(-p1));
                float s2v = p2 / (1.0f + expf(-p2));
                sg3[lm] = 0.5f * (s1v - s2v);
            }
        }
    } else {
        int rq = t & 31, hb = (t >> 5) & 3;
        float4 e1 = make_float4(0.f,0.f,0.f,0.f);
        float4 e2 = make_float4(0.f,0.f,0.f,0.f);
        #pragma unroll 4
        for (int mi = 0; mi < 32; mi++) {
            float ri = srinv[mi];
            float a1 = sattn[hb*36 + mi] * ri;
            float a2 = sattn[(hb+4)*36 + mi] * ri;
            float4 x4 = *(const float4*)&se[mi*132 + 4*rq];
            e1.x += a1*x4.x; e1.y += a1*x4.y; e1.z += a1*x4.z; e1.w += a1*x4.w;
            e2.x += a2*x4.x; e2.y += a2*x4.y; e2.z += a2*x4.z; e2.w += a2*x4.w;
        }
        float4 g4 = *(const float4*)&lneg[4*rq];
        float4 b4 = *(const float4*)&lneb[4*rq];
        float4 o1, o2;
        o1.x = g4.x*e1.x + b4.x; o1.y = g4.y*e1.y + b4.y;
        o1.z = g4.z*e1.z + b4.z; o1.w = g4.w*e1.w + b4.w;
        o2.x = g4.x*e2.x + b4.x; o2.y = g4.y*e2.y + b4.y;
        o2.z = g4.z*e2.z + b4.z; o2.w = g4.w*e2.w + b4.w;
        *(float4*)&sew[hb*132 + 4*rq]     = o1;
        *(float4*)&sew[(hb+4)*132 + 4*rq] = o2;
    }
    __syncthreads();   // bar4

    // ---- P4: edge ctx GEMM, in-wave K-split 8 (r = ri*8+ks), no bar5 ----
    {
        int col4 = t >> 3, ks = t & 7;      // col4 0..31, ks 0..7
        int h2 = col4 >> 2;
        const float* wqb = Wqkve + 128 + 4*col4;
        float4 accE = make_float4(0.f,0.f,0.f,0.f);
        #pragma unroll 4
        for (int ri = 0; ri < 16; ri++) {
            int r = ri*8 + ks;
            float sv = sew[h2*132 + r];
            float4 w4 = *(const float4*)&wqb[(size_t)r*256];
            accE.x += sv*w4.x; accE.y += sv*w4.y; accE.z += sv*w4.z; accE.w += sv*w4.w;
        }
        #pragma unroll
        for (int st = 1; st < 8; st <<= 1) {
            accE.x += __shfl_xor(accE.x, st, 8);
            accE.y += __shfl_xor(accE.y, st, 8);
            accE.z += __shfl_xor(accE.z, st, 8);
            accE.w += __shfl_xor(accE.w, st, 8);
        }
        if (ks == 0) {
            float4 b4 = *(const float4*)&bqkve[128 + 4*col4];
            accE.x += b4.x; accE.y += b4.y; accE.z += b4.z; accE.w += b4.w;
            *(float4*)&ws[OFF_HCAT + (size_t)n*384 + 256 + 4*col4] = accE;
        }
    }

    if (t < 3) {
        const float* Vm = ws + OFF_VMAT + g*9;
        float gc = Vm[t*3+0]*sg3[0] + Vm[t*3+1]*sg3[1] + Vm[t*3+2]*sg3[2] + ws[OFF_CEN + g*3 + t];
        float gt = ws[OFF_GATE + n];
        out[OUT_GEO_OFF + (size_t)n*3 + t] = gc * gt + geo[(size_t)n*3 + t] * (1.0f - gt);
    }
}

// ---------------- Kernel 4: MLP — 8 tokens/block, K-split halves -----------
__global__ __launch_bounds__(256) void k_mlp(
    const float* __restrict__ tok, const float* __restrict__ Wfc1,
    const float* __restrict__ bfc1, const float* __restrict__ lnhg,
    const float* __restrict__ lnhb, const float* __restrict__ Wfc2,
    const float* __restrict__ bfc2, const float* __restrict__ ws,
    float* __restrict__ out)
{
    __shared__ __align__(16) float A[384 * 12];   // [k][8 tokens + pad]
    __shared__ __align__(16) float R[128 * 16];   // cross-half reduce
    int t = threadIdx.x;
    int tok0 = blockIdx.x * 8;
    int i2 = (t >> 6) & 1, kh = t >> 7, j = t & 63;
    const float* hc = ws + OFF_HCAT;

    #pragma unroll
    for (int q = 0; q < 12; q++) {
        int idx = q*256 + t;
        int tt = idx / 384;
        int k  = idx - tt*384;
        A[k*12 + tt] = hc[(size_t)tok0*384 + idx];
    }
    __syncthreads();

    // fc1 (half K per thread)
    float4 acc1[4];
    acc1[0] = acc1[1] = acc1[2] = acc1[3] = make_float4(0.f,0.f,0.f,0.f);
    {
        const float* wp = Wfc1 + 4*j;
        int kbase = kh * 192;
        #pragma unroll 8
        for (int kk = 0; kk < 192; kk++) {
            int k = kbase + kk;
            float4 a4 = *(const float4*)&A[k*12 + 4*i2];
            float4 w4 = *(const float4*)&wp[(size_t)k*256];
            fma4x4(a4, w4, acc1);
        }
    }
    if (kh == 1) {
        int rowid = t - 128;
        #pragma unroll
        for (int ti = 0; ti < 4; ti++) *(float4*)&R[rowid*16 + ti*4] = acc1[ti];
    }
    __syncthreads();

    float h[4][4];
    if (kh == 0) {
        float4 b4 = *(const float4*)&bfc1[4*j];
        #pragma unroll
        for (int ti = 0; ti < 4; ti++) {
            float4 p = *(const float4*)&R[t*16 + ti*4];
            float xv[4] = {acc1[ti].x + p.x + b4.x, acc1[ti].y + p.y + b4.y,
                           acc1[ti].z + p.z + b4.z, acc1[ti].w + p.w + b4.w};
            #pragma unroll
            for (int c = 0; c < 4; c++) {
                float x = xv[c];
                h[ti][c] = 0.5f * x * (1.0f + erff(x * 0.70710678118654752f));
            }
        }
        // LN across the 64 j-lanes (wave i2 shares tokens 4i2..4i2+3)
        float s[4], qv[4];
        #pragma unroll
        for (int ti = 0; ti < 4; ti++) {
            s[ti]  = h[ti][0] + h[ti][1] + h[ti][2] + h[ti][3];
            qv[ti] = h[ti][0]*h[ti][0] + h[ti][1]*h[ti][1] + h[ti][2]*h[ti][2] + h[ti][3]*h[ti][3];
        }
        for (int m = 32; m >= 1; m >>= 1)
            #pragma unroll
            for (int ti = 0; ti < 4; ti++) {
                s[ti]  += __shfl_xor(s[ti], m, 64);
                qv[ti] += __shfl_xor(qv[ti], m, 64);
            }
        float4 g4 = *(const float4*)&lnhg[4*j];
        float4 b42 = *(const float4*)&lnhb[4*j];
        float gg[4] = {g4.x, g4.y, g4.z, g4.w};
        float bb[4] = {b42.x, b42.y, b42.z, b42.w};
        #pragma unroll
        for (int ti = 0; ti < 4; ti++) {
            float mu = s[ti] * (1.0f/256.0f);
            float var = qv[ti] * (1.0f/256.0f) - mu*mu;
            float rinv = rsqrtf(var + 1e-5f);
            #pragma unroll
            for (int c = 0; c < 4; c++) {
                float hn = (h[ti][c] - mu) * rinv * gg[c] + bb[c];
                A[(4*j + c)*12 + 4*i2 + ti] = hn;
            }
        }
    }
    __syncthreads();

    // fc2 (half K per thread)
    float4 acc2[4];
    acc2[0] = acc2[1] = acc2[2] = acc2[3] = make_float4(0.f,0.f,0.f,0.f);
    {
        const float* wp = Wfc2 + 4*j;
        int kbase = kh * 128;
        #pragma unroll 8
        for (int kk = 0; kk < 128; kk++) {
            int k = kbase + kk;
            float4 a4 = *(const float4*)&A[k*12 + 4*i2];
            float4 w4 = *(const float4*)&wp[(size_t)k*256];
            fma4x4(a4, w4, acc2);
        }
    }
    if (kh == 1) {
        int rowid = t - 128;
        #pragma unroll
        for (int ti = 0; ti < 4; ti++) *(float4*)&R[rowid*16 + ti*4] = acc2[ti];
    }
    __syncthreads();

    if (kh == 0) {
        float4 b4 = *(const float4*)&bfc2[4*j];
        #pragma unroll
        for (int ti = 0; ti < 4; ti++) {
            float4 p = *(const float4*)&R[t*16 + ti*4];
            size_t o = (size_t)(tok0 + 4*i2 + ti) * 256 + 4*j;
            float4 r4 = *(const float4*)&tok[o];
            float4 v;
            v.x = acc2[ti].x + p.x + b4.x + r4.x;
            v.y = acc2[ti].y + p.y + b4.y + r4.y;
            v.z = acc2[ti].z + p.z + b4.z + r4.z;
            v.w = acc2[ti].w + p.w + b4.w + r4.w;
            *(float4*)&out[o] = v;
        }
    }
}

extern "C" void kernel_launch(void* const* d_in, const int* in_sizes, int n_in,
                              void* d_out, int out_size, void* d_ws, size_t ws_size,
                              hipStream_t stream) {
    (void)in_sizes; (void)n_in; (void)out_size; (void)ws_size;
    const float* tok   = (const float*)d_in[0];
    const float* geo   = (const float*)d_in[1];
    const float* edge  = (const float*)d_in[2];
    const int*   nbr   = (const int*)d_in[3];
    const void*  maskp = d_in[5];
    const float* ln_qkv_g = (const float*)d_in[6];
    const float* ln_qkv_b = (const float*)d_in[7];
    const float* Wqkv  = (const float*)d_in[8];
    const float* bqkv  = (const float*)d_in[9];
    const float* ln_e_g = (const float*)d_in[10];
    const float* ln_e_b = (const float*)d_in[11];
    const float* Wqkve = (const float*)d_in[12];
    const float* bqkve = (const float*)d_in[13];
    const float* w_attn = (const float*)d_in[14];
    const float* w_edge = (const float*)d_in[15];
    const float* Wgate = (const float*)d_in[16];
    const float* bgate = (const float*)d_in[17];
    const float* Wfc1  = (const float*)d_in[18];
    const float* bfc1  = (const float*)d_in[19];
    const float* lnhg  = (const float*)d_in[20];
    const float* lnhb  = (const float*)d_in[21];
    const float* Wfc2  = (const float*)d_in[22];
    const float* bfc2  = (const float*)d_in[23];
    const float* Wfa   = (const float*)d_in[24];
    const float* bfa   = (const float*)d_in[25];
    float* ws  = (float*)d_ws;
    float* out = (float*)d_out;

    k_pre<<<dim3(38), dim3(256), 0, stream>>>(Wqkv, bqkv, Wqkve, bqkve, w_attn, w_edge,
                                              ln_e_g, ln_e_b, (const int*)maskp, geo, ws);
    k_tokprep<<<dim3(1024), dim3(256), 0, stream>>>(tok, ln_qkv_g, ln_qkv_b, Wgate, bgate,
                                                    Wqkv, bqkv, ws);
    k_attn<<<dim3(8192), dim3(256), 0, stream>>>(edge, nbr, maskp, ln_e_g, ln_e_b, bqkve,
                                                 Wqkve, Wfa, bfa, geo, ws, out);
    k_mlp<<<dim3(1024), dim3(256), 0, stream>>>(tok, Wfc1, bfc1, lnhg, lnhb, Wfc2, bfc2, ws, out);
}

// Round 4
// 397.701 us; speedup vs baseline: 1.0642x; 1.0642x over previous
//
#include <hip/hip_runtime.h>
#include <math.h>

#define NTOK 8192
#define NPG  512
#define MNEI 32
#define DM   256
#define DE   128
#define NH   8

// workspace offsets (in floats)
#define OFF_WQAK  65536u      // 16*256   [c][k] qa/ka transposed
#define OFF_BCAT  69632u      // 16 (cols 0..7 qa bias + edge-LN const fold, 8..15 ka bias)
#define OFF_WEF   69904u      // 8*128  [h][r]  wg = wef * ln_e_g  (LN gain folded)
#define OFF_FLAG  70936u      // 1 int
#define OFF_QA    70944u      // 8192*8
#define OFF_KA    136480u     // 8192*8
#define OFF_GATE  202016u     // 8192
#define OFF_VW    210208u     // 8192*256
#define OFF_PROJ  2307360u    // 8192*3
#define OFF_VMAT  2331936u    // 16*9
#define OFF_CEN   2332080u    // 16*3
#define OFF_HCAT  2332128u    // 8192*384

#define OUT_GEO_OFF 2097152   // 8192*256

__device__ __forceinline__ void fma4x4(const float4 a, const float4 w, float4* acc) {
    acc[0].x += a.x*w.x; acc[0].y += a.x*w.y; acc[0].z += a.x*w.z; acc[0].w += a.x*w.w;
    acc[1].x += a.y*w.x; acc[1].y += a.y*w.y; acc[1].z += a.y*w.z; acc[1].w += a.y*w.w;
    acc[2].x += a.z*w.x; acc[2].y += a.z*w.y; acc[2].z += a.z*w.z; acc[2].w += a.z*w.w;
    acc[3].x += a.w*w.x; acc[3].y += a.w*w.y; acc[3].z += a.w*w.z; acc[3].w += a.w*w.w;
}

__device__ __forceinline__ float dot4(const float4 a, const float4 b) {
    return a.x*b.x + a.y*b.y + a.z*b.z + a.w*b.w;
}

// ---------------- Kernel 1: merged preprocessing --------------------------
// block 0: mask layout detect; block 1: BCAT[0..15] (parallel fold);
// blocks 2..17: WQAK (c = b-2); blocks 18..21: WEF; blocks 22..37: per-graph
// geometry (center, cov, eigh, proj). All parts independent.
__global__ __launch_bounds__(256) void k_pre(
    const float* __restrict__ Wqkv, const float* __restrict__ bqkv,
    const float* __restrict__ Wqkve, const float* __restrict__ bqkve,
    const float* __restrict__ w_attn, const float* __restrict__ w_edge,
    const float* __restrict__ lneg, const float* __restrict__ lneb,
    const int* __restrict__ maskp, const float* __restrict__ geo,
    float* __restrict__ ws)
{
    int t = threadIdx.x;
    int b = blockIdx.x;

    if (b == 0) {
        // ---- mask layout detection ----
        __shared__ int sbad, sflt;
        if (t == 0) { sbad = 0; sflt = 0; }
        __syncthreads();
        int bad = 0, flt = 0;
        for (int i = 0; i < 256; i++) {
            unsigned int w = (unsigned int)maskp[i*256 + t];
            if (w > 1u) bad = 1;
            if (w == 0x3F800000u) flt = 1;
        }
        if (bad) atomicOr(&sbad, 1);
        if (flt) atomicOr(&sflt, 1);
        __syncthreads();
        if (t == 0) {
            int f = sflt ? 2 : (sbad ? 1 : 0);
            ((int*)(ws + OFF_FLAG))[0] = f;
        }
        return;
    }
    if (b == 1) {
        // ---- BCAT[0..15]: qa bias + edge-LN const fold, ka bias ----
        int h = t >> 5, l = t & 31;
        float p = 0.f;
        for (int q = 0; q < 4; q++) {
            int r = l + 32*q;
            float wef = 0.f;
            for (int e = 0; e < 16; e++) wef += Wqkve[r*256 + h*16 + e] * w_edge[e];
            p += lneb[r] * wef;
        }
        for (int m = 16; m >= 1; m >>= 1) p += __shfl_xor(p, m, 32);
        if (l == 0) {
            float s = p;
            for (int d = 0; d < 32; d++) s += bqkv[h*32 + d] * w_attn[d];
            for (int e = 0; e < 16; e++) s += bqkve[h*16 + e] * w_edge[e];
            ws[OFF_BCAT + h] = s;
        }
        if (l == 1) {
            float s = 0.f;
            for (int d = 0; d < 32; d++) s += bqkv[256 + h*32 + d] * w_attn[d];
            ws[OFF_BCAT + 8 + h] = s;
        }
        return;
    }
    if (b < 18) {
        // ---- WQAK: c = b-2, one k per thread ----
        int c = b - 2, k = t;
        int h = c & 7; int off = (c < 8) ? 0 : 256;
        float s = 0.f;
        for (int d = 0; d < 32; d++) s += Wqkv[k*768 + off + h*32 + d] * w_attn[d];
        ws[OFF_WQAK + c*256 + k] = s;
        return;
    }
    if (b < 22) {
        // ---- WEF: wg[h][r] = (Σ_e Wqkve·w_edge) · lneg[r] ----
        int i = (b - 18)*256 + t;
        int h = i >> 7, r = i & 127;
        float s = 0.f;
        for (int e = 0; e < 16; e++) s += Wqkve[r*256 + h*16 + e] * w_edge[e];
        ws[OFF_WEF + i] = s * lneg[r];
        return;
    }

    // ---- per-graph geometry: g = b - 22 ----
    {
        __shared__ float sred[4 * 9];
        __shared__ float sres[9];
        __shared__ float sV[9];
        int g = b - 22;
        int wave = t >> 6, lane = t & 63;
        const float* gp = geo + (size_t)g * NPG * 3;

        float x0[2], y0[2], z0[2];
        float sx = 0.f, sy = 0.f, sz = 0.f;
        for (int i = 0; i < 2; i++) {
            int p = t + 256 * i;
            x0[i] = gp[p*3 + 0]; y0[i] = gp[p*3 + 1]; z0[i] = gp[p*3 + 2];
            sx += x0[i]; sy += y0[i]; sz += z0[i];
        }
        {
            float vals[3] = {sx, sy, sz};
            for (int q = 0; q < 3; q++) {
                float v = vals[q];
                for (int m = 32; m >= 1; m >>= 1) v += __shfl_xor(v, m, 64);
                if (lane == 0) sred[wave*9 + q] = v;
            }
        }
        __syncthreads();
        if (t < 3) {
            float s = 0.f;
            for (int w = 0; w < 4; w++) s += sred[w*9 + t];
            sres[t] = s * (1.0f / 512.0f);
        }
        __syncthreads();
        float cx = sres[0], cy = sres[1], cz = sres[2];

        float c6[6] = {0.f, 0.f, 0.f, 0.f, 0.f, 0.f};
        for (int i = 0; i < 2; i++) {
            float dx = x0[i] - cx, dy = y0[i] - cy, dz = z0[i] - cz;
            c6[0] += dx*dx; c6[1] += dx*dy; c6[2] += dx*dz;
            c6[3] += dy*dy; c6[4] += dy*dz; c6[5] += dz*dz;
        }
        for (int q = 0; q < 6; q++) {
            float v = c6[q];
            for (int m = 32; m >= 1; m >>= 1) v += __shfl_xor(v, m, 64);
            if (lane == 0) sred[wave*9 + q] = v;
        }
        __syncthreads();
        if (t < 6) {
            float s = 0.f;
            for (int w = 0; w < 4; w++) s += sred[w*9 + t];
            sres[t] = s;
        }
        __syncthreads();

        if (t == 0) {
            double a[3][3];
            a[0][0] = sres[0]; a[0][1] = a[1][0] = sres[1]; a[0][2] = a[2][0] = sres[2];
            a[1][1] = sres[3]; a[1][2] = a[2][1] = sres[4]; a[2][2] = sres[5];
            double v[3][3] = {{1,0,0},{0,1,0},{0,0,1}};
            const int ps[3] = {0, 0, 1}, qs[3] = {1, 2, 2};
            for (int sweep = 0; sweep < 10; sweep++) {
                for (int pi = 0; pi < 3; pi++) {
                    int p = ps[pi], q = qs[pi];
                    double apq = a[p][q];
                    if (fabs(apq) < 1e-300) continue;
                    double theta = (a[q][q] - a[p][p]) / (2.0 * apq);
                    double tt = ((theta >= 0.0) ? 1.0 : -1.0) / (fabs(theta) + sqrt(theta*theta + 1.0));
                    double c = 1.0 / sqrt(tt*tt + 1.0), s = tt * c;
                    int k = 3 - p - q;
                    double app = a[p][p], aqq = a[q][q], akp = a[k][p], akq = a[k][q];
                    a[p][p] = app - tt * apq;
                    a[q][q] = aqq + tt * apq;
                    a[p][q] = 0.0; a[q][p] = 0.0;
                    a[k][p] = c*akp - s*akq; a[p][k] = a[k][p];
                    a[k][q] = s*akp + c*akq; a[q][k] = a[k][q];
                    for (int kk = 0; kk < 3; kk++) {
                        double vp = v[kk][p], vq = v[kk][q];
                        v[kk][p] = c*vp - s*vq;
                        v[kk][q] = s*vp + c*vq;
                    }
                }
            }
            for (int r = 0; r < 3; r++)
                for (int c2 = 0; c2 < 3; c2++) {
                    float fv = (float)v[r][c2];
                    sV[r*3 + c2] = fv;
                    ws[OFF_VMAT + g*9 + r*3 + c2] = fv;
                }
            ws[OFF_CEN + g*3 + 0] = cx;
            ws[OFF_CEN + g*3 + 1] = cy;
            ws[OFF_CEN + g*3 + 2] = cz;
        }
        __syncthreads();

        for (int i = 0; i < 2; i++) {
            int p = t + 256 * i;
            float dx = x0[i] - cx, dy = y0[i] - cy, dz = z0[i] - cz;
            for (int c = 0; c < 3; c++) {
                float pr = dx * sV[0*3 + c] + dy * sV[1*3 + c] + dz * sV[2*3 + c];
                ws[OFF_PROJ + (size_t)(g*NPG + p)*3 + c] = pr;
            }
        }
    }
}

// ---------------- Kernel 2: token LN + gate + [qa|ka|v] ---------------------
// v3: v-GEMM rebalanced across ALL 4 waves (thread: 2 tokens x 4 cols,
// full K=256, 2048 FMA) reading Wqkv directly (stride-768 coalesced float4).
// qa/ka afterwards on t<128 (no barrier needed; sln is stable).
__global__ __launch_bounds__(256) void k_tokprep(
    const float* __restrict__ tok, const float* __restrict__ ln_g,
    const float* __restrict__ ln_b, const float* __restrict__ Wgate,
    const float* __restrict__ bgate, const float* __restrict__ Wqkv,
    const float* __restrict__ bqkv, float* __restrict__ ws)
{
    __shared__ __align__(16) float sln[256 * 12];   // [k][8 tokens + pad]
    int t = threadIdx.x;
    int tok0 = blockIdx.x * 8;

    #pragma unroll
    for (int q = 0; q < 8; q++)
        sln[t*12 + q] = tok[(size_t)(tok0 + q) * 256 + t];
    __syncthreads();

    int wave = t >> 6, lane = t & 63;
    for (int rr = 0; rr < 2; rr++) {
        int tt = wave * 2 + rr;
        float s = 0.f, gdot = 0.f;
        float xs[4];
        #pragma unroll
        for (int q = 0; q < 4; q++) {
            int k = lane + 64*q;
            float x = sln[k*12 + tt];
            xs[q] = x; s += x; gdot += x * Wgate[k];
        }
        for (int m = 32; m >= 1; m >>= 1) { s += __shfl_xor(s,m,64); gdot += __shfl_xor(gdot,m,64); }
        float mu = s * (1.0f/256.0f);
        float vs = 0.f;
        #pragma unroll
        for (int q = 0; q < 4; q++) { float d = xs[q]-mu; vs += d*d; }
        for (int m = 32; m >= 1; m >>= 1) vs += __shfl_xor(vs,m,64);
        float rinv = rsqrtf(vs*(1.0f/256.0f)+1e-5f);
        #pragma unroll
        for (int q = 0; q < 4; q++) {
            int k = lane + 64*q;
            sln[k*12 + tt] = (xs[q]-mu)*rinv*ln_g[k] + ln_b[k];
        }
        if (lane == 0) ws[OFF_GATE + tok0 + tt] = 1.0f/(1.0f+expf(-(gdot + bgate[0])));
    }
    __syncthreads();

    // ---- v-GEMM: all waves; thread (i = t>>6 -> tokens 2i,2i+1; j = t&63) ----
    {
        int i = t >> 6, j = t & 63;
        const float* Wc = Wqkv + 512 + 4*j;
        float4 acc0 = make_float4(0.f,0.f,0.f,0.f);
        float4 acc1 = make_float4(0.f,0.f,0.f,0.f);
        #pragma unroll 8
        for (int k = 0; k < 256; k++) {
            float a0 = sln[k*12 + 2*i];
            float a1 = sln[k*12 + 2*i + 1];
            float4 w4 = *(const float4*)&Wc[(size_t)k*768];
            acc0.x += a0*w4.x; acc0.y += a0*w4.y; acc0.z += a0*w4.z; acc0.w += a0*w4.w;
            acc1.x += a1*w4.x; acc1.y += a1*w4.y; acc1.z += a1*w4.z; acc1.w += a1*w4.w;
        }
        float4 b4 = *(const float4*)&bqkv[512 + 4*j];
        int n0 = tok0 + 2*i;
        acc0.x += b4.x; acc0.y += b4.y; acc0.z += b4.z; acc0.w += b4.w;
        acc1.x += b4.x; acc1.y += b4.y; acc1.z += b4.z; acc1.w += b4.w;
        *(float4*)&ws[OFF_VW + (size_t)n0*256 + 4*j]     = acc0;
        *(float4*)&ws[OFF_VW + (size_t)(n0+1)*256 + 4*j] = acc1;
    }

    // ---- qa/ka: t<128 (col = t&15, token tp = t>>4) ----
    if (t < 128) {
        int col = t & 15, tp = t >> 4;
        const float* wq = ws + OFF_WQAK + col*256;
        float acc = 0.f;
        #pragma unroll 8
        for (int k4 = 0; k4 < 64; k4++) {
            float4 w4 = *(const float4*)&wq[4*k4];
            acc += w4.x * sln[(4*k4+0)*12 + tp]
                 + w4.y * sln[(4*k4+1)*12 + tp]
                 + w4.z * sln[(4*k4+2)*12 + tp]
                 + w4.w * sln[(4*k4+3)*12 + tp];
        }
        acc += ws[OFF_BCAT + col];
        int n = tok0 + tp;
        if (col < 8) ws[OFF_QA + n*8 + col] = acc;
        else         ws[OFF_KA + n*8 + (col - 8)] = acc;
    }
}

// ---------------- Kernel 3: fused per-token attention (LN-folded) ----------
// v4: P4 reverted to coalesced row-group K-split (sec LDS reduce, bar5) —
// the in-wave K-split scattered Wqkve reads (4x L1 amplification, -30us).
// New: qa/ka/mask loads issued in P0 (per-thread nbr read) so their latency
// hides under uSWE staging + bar1 instead of serializing in P1.
// 5 barriers. LDS 22.5 KB -> 7 blocks/CU.
__global__ __launch_bounds__(256) void k_attn(
    const float* __restrict__ edge, const int* __restrict__ nbr,
    const void* __restrict__ maskp,
    const float* __restrict__ lneg, const float* __restrict__ lneb,
    const float* __restrict__ bqkve, const float* __restrict__ Wqkve,
    const float* __restrict__ Wfa, const float* __restrict__ bfa,
    const float* __restrict__ geo, float* __restrict__ ws, float* __restrict__ out)
{
    __shared__ __align__(16) float se[32 * 132];    // centered edge rows; sec aliases in P4
    __shared__ __align__(16) float uSWE[8 * 132];   // [sub][h][16] wg; sew aliases after logits
    __shared__ __align__(16) float sattn[8 * 36];   // logits -> attn (in place)
    __shared__ float srinv[32];
    __shared__ int   snbr[32];
    __shared__ float sg3[4];

    int t = threadIdx.x;
    int n = blockIdx.x;
    int g = n >> 9;
    int flag = ((const int*)(ws + OFF_FLAG))[0];

    int m = t >> 3, sub = t & 7;

    // ---- P0: direct global->reg row load + early scalar-path loads ----
    const float4* xp = (const float4*)(edge + (size_t)n * 4096 + m*128 + sub*16);
    float4 x0 = xp[0], x1 = xp[1], x2 = xp[2], x3 = xp[3];

    // early: neighbor index (8 lanes/row same word -> L1 broadcast), qa, ka, mask
    int nb = nbr[n*32 + m];
    float qa = ws[OFF_QA + n*8 + sub];
    float ka = ws[OFF_KA + (size_t)nb*8 + sub];
    int mv;
    if (flag == 1)      mv = (int)((const unsigned char*)maskp)[n*32 + m];
    else if (flag == 2) mv = (((const float*)maskp)[n*32 + m] != 0.0f) ? 1 : 0;
    else                mv = ((const int*)maskp)[n*32 + m];

    {
        // wg weights re-laid out sub-major: uSWE[s2*132 + h*16 + c]
        int idx = t * 4;
        int h = idx >> 7, r = idx & 127;
        int s2 = r >> 4, c = r & 15;
        *(float4*)&uSWE[s2*132 + h*16 + c] = *(const float4*)&ws[OFF_WEF + idx];
    }
    if (t < 32) snbr[t] = nbr[n*32 + t];
    __syncthreads();   // bar1

    // ---- P1: row stats + centered-row LDS write + logits from registers ----
    {
        float s = x0.x+x0.y+x0.z+x0.w + x1.x+x1.y+x1.z+x1.w
                + x2.x+x2.y+x2.z+x2.w + x3.x+x3.y+x3.z+x3.w;
        for (int mm = 4; mm >= 1; mm >>= 1) s += __shfl_xor(s, mm, 8);
        float mu = s * (1.0f / 128.0f);
        x0.x-=mu; x0.y-=mu; x0.z-=mu; x0.w-=mu;
        x1.x-=mu; x1.y-=mu; x1.z-=mu; x1.w-=mu;
        x2.x-=mu; x2.y-=mu; x2.z-=mu; x2.w-=mu;
        x3.x-=mu; x3.y-=mu; x3.z-=mu; x3.w-=mu;
        float vs = dot4(x0,x0) + dot4(x1,x1) + dot4(x2,x2) + dot4(x3,x3);
        for (int mm = 4; mm >= 1; mm >>= 1) vs += __shfl_xor(vs, mm, 8);
        float rinv = rsqrtf(vs * (1.0f / 128.0f) + 1e-5f);
        float4* sp = (float4*)&se[m*132 + sub*16];
        sp[0] = x0; sp[1] = x1; sp[2] = x2; sp[3] = x3;
        if (sub == 0) srinv[m] = rinv;

        // logits: dot(wg[h], x - mu) for all h, butterfly over 8 sub-lanes
        float accl[8];
        const float* wb = &uSWE[sub*132];
        #pragma unroll
        for (int h = 0; h < 8; h++) {
            const float4* wp = (const float4*)(wb + h*16);
            accl[h] = dot4(x0,wp[0]) + dot4(x1,wp[1]) + dot4(x2,wp[2]) + dot4(x3,wp[3]);
        }
        #pragma unroll
        for (int st = 1; st < 8; st <<= 1) {
            #pragma unroll
            for (int h = 0; h < 8; h++) accl[h] += __shfl_xor(accl[h], st, 8);
        }
        float myacc = accl[0];
        #pragma unroll
        for (int h = 1; h < 8; h++) myacc = (sub == h) ? accl[h] : myacc;

        float lg = myacc * rinv + qa + ka;
        if (!mv) lg = -1e9f;
        sattn[sub*36 + m] = lg;
    }
    __syncthreads();   // bar2

    // ---- P2: softmax over m per h (in place) ----
    {
        int h = t >> 5, m2 = t & 31;
        float x = sattn[h*36 + m2];
        float mx = x;
        for (int mm = 16; mm >= 1; mm >>= 1) mx = fmaxf(mx, __shfl_xor(mx, mm, 32));
        float e = expf(x - mx);
        float sum = e;
        for (int mm = 16; mm >= 1; mm >>= 1) sum += __shfl_xor(sum, mm, 32);
        sattn[h*36 + m2] = e / sum;
    }
    __syncthreads();   // bar3 (uSWE dead -> sew aliases it)

    float* sew = uSWE;

    // ---- P3: wave-specialized: sctx gather | geo | weighted centered rows ----
    int wave = t >> 6;
    if (wave == 0) {
        int c4 = t, h = c4 >> 3;
        const float* vw = ws + OFF_VW;
        float4 acc = make_float4(0.f,0.f,0.f,0.f);
        #pragma unroll 4
        for (int mi = 0; mi < 32; mi++) {
            float a = sattn[h*36 + mi];
            int row = snbr[mi];
            float4 v4 = *(const float4*)&vw[(size_t)row*256 + 4*c4];
            acc.x += a*v4.x; acc.y += a*v4.y; acc.z += a*v4.z; acc.w += a*v4.w;
        }
        *(float4*)&ws[OFF_HCAT + (size_t)n*384 + 4*c4] = acc;
    } else if (wave == 1) {
        int lm = t - 64;
        if (lm < 32) {
            float wmv = 0.f;
            #pragma unroll
            for (int h2 = 0; h2 < 8; h2++) wmv += Wfa[h2] * sattn[h2*36 + lm];
            int row = snbr[lm];
            const float* pp = ws + OFF_PROJ + (size_t)row*3;
            float q0 = wmv * pp[0], q1 = wmv * pp[1], q2 = wmv * pp[2];
            for (int st = 16; st >= 1; st >>= 1) {
                q0 += __shfl_xor(q0, st, 32);
                q1 += __shfl_xor(q1, st, 32);
                q2 += __shfl_xor(q2, st, 32);
            }
            if (lm < 3) {
                float sd = (lm == 0) ? q0 : (lm == 1) ? q1 : q2;
                float bb = bfa[0];
                float p1 = sd + bb, p2 = -sd + bb;
                float s1v = p1 / (1.0f + expf(-p1));
                float s2v = p2 / (1.0f + expf(-p2));
                sg3[lm] = 0.5f * (s1v - s2v);
            }
        }
    } else {
        int rq = t & 31, hb = (t >> 5) & 3;
        float4 e1 = make_float4(0.f,0.f,0.f,0.f);
        float4 e2 = make_float4(0.f,0.f,0.f,0.f);
        #pragma unroll 4
        for (int mi = 0; mi < 32; mi++) {
            float ri = srinv[mi];
            float a1 = sattn[hb*36 + mi] * ri;
            float a2 = sattn[(hb+4)*36 + mi] * ri;
            float4 x4 = *(const float4*)&se[mi*132 + 4*rq];
            e1.x += a1*x4.x; e1.y += a1*x4.y; e1.z += a1*x4.z; e1.w += a1*x4.w;
            e2.x += a2*x4.x; e2.y += a2*x4.y; e2.z += a2*x4.z; e2.w += a2*x4.w;
        }
        float4 g4 = *(const float4*)&lneg[4*rq];
        float4 b4 = *(const float4*)&lneb[4*rq];
        float4 o1, o2;
        o1.x = g4.x*e1.x + b4.x; o1.y = g4.y*e1.y + b4.y;
        o1.z = g4.z*e1.z + b4.z; o1.w = g4.w*e1.w + b4.w;
        o2.x = g4.x*e2.x + b4.x; o2.y = g4.y*e2.y + b4.y;
        o2.z = g4.z*e2.z + b4.z; o2.w = g4.w*e2.w + b4.w;
        *(float4*)&sew[hb*132 + 4*rq]     = o1;
        *(float4*)&sew[(hb+4)*132 + 4*rq] = o2;
    }
    __syncthreads();   // bar4 (se dead; sec aliases it)

    // ---- P4: edge ctx GEMM (coalesced float4, K-split 8 row-groups) ----
    float* sec = se;
    {
        int col4 = t & 31, rgrp = t >> 5;
        int h2 = col4 >> 2;
        const float* wqb = Wqkve + 128 + 4*col4;
        float4 accE = make_float4(0.f,0.f,0.f,0.f);
        #pragma unroll 4
        for (int ri = 0; ri < 16; ri++) {
            int r = rgrp*16 + ri;
            float sv = sew[h2*132 + r];
            float4 w4 = *(const float4*)&wqb[(size_t)r*256];
            accE.x += sv*w4.x; accE.y += sv*w4.y; accE.z += sv*w4.z; accE.w += sv*w4.w;
        }
        *(float4*)&sec[rgrp*128 + 4*col4] = accE;
    }
    __syncthreads();   // bar5

    if (t < 128) {
        float ec = bqkve[128 + t];
        #pragma unroll
        for (int g2 = 0; g2 < 8; g2++) ec += sec[g2*128 + t];
        ws[OFF_HCAT + (size_t)n*384 + 256 + t] = ec;
    }
    if (t < 3) {
        const float* Vm = ws + OFF_VMAT + g*9;
        float gc = Vm[t*3+0]*sg3[0] + Vm[t*3+1]*sg3[1] + Vm[t*3+2]*sg3[2] + ws[OFF_CEN + g*3 + t];
        float gt = ws[OFF_GATE + n];
        out[OUT_GEO_OFF + (size_t)n*3 + t] = gc * gt + geo[(size_t)n*3 + t] * (1.0f - gt);
    }
}

// ---------------- Kernel 4: MLP — 8 tokens/block, K-split halves -----------
__global__ __launch_bounds__(256) void k_mlp(
    const float* __restrict__ tok, const float* __restrict__ Wfc1,
    const float* __restrict__ bfc1, const float* __restrict__ lnhg,
    const float* __restrict__ lnhb, const float* __restrict__ Wfc2,
    const float* __restrict__ bfc2, const float* __restrict__ ws,
    float* __restrict__ out)
{
    __shared__ __align__(16) float A[384 * 12];   // [k][8 tokens + pad]
    __shared__ __align__(16) float R[128 * 16];   // cross-half reduce
    int t = threadIdx.x;
    int tok0 = blockIdx.x * 8;
    int i2 = (t >> 6) & 1, kh = t >> 7, j = t & 63;
    const float* hc = ws + OFF_HCAT;

    #pragma unroll
    for (int q = 0; q < 12; q++) {
        int idx = q*256 + t;
        int tt = idx / 384;
        int k  = idx - tt*384;
        A[k*12 + tt] = hc[(size_t)tok0*384 + idx];
    }
    __syncthreads();

    // fc1 (half K per thread)
    float4 acc1[4];
    acc1[0] = acc1[1] = acc1[2] = acc1[3] = make_float4(0.f,0.f,0.f,0.f);
    {
        const float* wp = Wfc1 + 4*j;
        int kbase = kh * 192;
        #pragma unroll 8
        for (int kk = 0; kk < 192; kk++) {
            int k = kbase + kk;
            float4 a4 = *(const float4*)&A[k*12 + 4*i2];
            float4 w4 = *(const float4*)&wp[(size_t)k*256];
            fma4x4(a4, w4, acc1);
        }
    }
    if (kh == 1) {
        int rowid = t - 128;
        #pragma unroll
        for (int ti = 0; ti < 4; ti++) *(float4*)&R[rowid*16 + ti*4] = acc1[ti];
    }
    __syncthreads();

    float h[4][4];
    if (kh == 0) {
        float4 b4 = *(const float4*)&bfc1[4*j];
        #pragma unroll
        for (int ti = 0; ti < 4; ti++) {
            float4 p = *(const float4*)&R[t*16 + ti*4];
            float xv[4] = {acc1[ti].x + p.x + b4.x, acc1[ti].y + p.y + b4.y,
                           acc1[ti].z + p.z + b4.z, acc1[ti].w + p.w + b4.w};
            #pragma unroll
            for (int c = 0; c < 4; c++) {
                float x = xv[c];
                h[ti][c] = 0.5f * x * (1.0f + erff(x * 0.70710678118654752f));
            }
        }
        // LN across the 64 j-lanes (wave i2 shares tokens 4i2..4i2+3)
        float s[4], qv[4];
        #pragma unroll
        for (int ti = 0; ti < 4; ti++) {
            s[ti]  = h[ti][0] + h[ti][1] + h[ti][2] + h[ti][3];
            qv[ti] = h[ti][0]*h[ti][0] + h[ti][1]*h[ti][1] + h[ti][2]*h[ti][2] + h[ti][3]*h[ti][3];
        }
        for (int m = 32; m >= 1; m >>= 1)
            #pragma unroll
            for (int ti = 0; ti < 4; ti++) {
                s[ti]  += __shfl_xor(s[ti], m, 64);
                qv[ti] += __shfl_xor(qv[ti], m, 64);
            }
        float4 g4 = *(const float4*)&lnhg[4*j];
        float4 b42 = *(const float4*)&lnhb[4*j];
        float gg[4] = {g4.x, g4.y, g4.z, g4.w};
        float bb[4] = {b42.x, b42.y, b42.z, b42.w};
        #pragma unroll
        for (int ti = 0; ti < 4; ti++) {
            float mu = s[ti] * (1.0f/256.0f);
            float var = qv[ti] * (1.0f/256.0f) - mu*mu;
            float rinv = rsqrtf(var + 1e-5f);
            #pragma unroll
            for (int c = 0; c < 4; c++) {
                float hn = (h[ti][c] - mu) * rinv * gg[c] + bb[c];
                A[(4*j + c)*12 + 4*i2 + ti] = hn;
            }
        }
    }
    __syncthreads();

    // fc2 (half K per thread)
    float4 acc2[4];
    acc2[0] = acc2[1] = acc2[2] = acc2[3] = make_float4(0.f,0.f,0.f,0.f);
    {
        const float* wp = Wfc2 + 4*j;
        int kbase = kh * 128;
        #pragma unroll 8
        for (int kk = 0; kk < 128; kk++) {
            int k = kbase + kk;
            float4 a4 = *(const float4*)&A[k*12 + 4*i2];
            float4 w4 = *(const float4*)&wp[(size_t)k*256];
            fma4x4(a4, w4, acc2);
        }
    }
    if (kh == 1) {
        int rowid = t - 128;
        #pragma unroll
        for (int ti = 0; ti < 4; ti++) *(float4*)&R[rowid*16 + ti*4] = acc2[ti];
    }
    __syncthreads();

    if (kh == 0) {
        float4 b4 = *(const float4*)&bfc2[4*j];
        #pragma unroll
        for (int ti = 0; ti < 4; ti++) {
            float4 p = *(const float4*)&R[t*16 + ti*4];
            size_t o = (size_t)(tok0 + 4*i2 + ti) * 256 + 4*j;
            float4 r4 = *(const float4*)&tok[o];
            float4 v;
            v.x = acc2[ti].x + p.x + b4.x + r4.x;
            v.y = acc2[ti].y + p.y + b4.y + r4.y;
            v.z = acc2[ti].z + p.z + b4.z + r4.z;
            v.w = acc2[ti].w + p.w + b4.w + r4.w;
            *(float4*)&out[o] = v;
        }
    }
}

extern "C" void kernel_launch(void* const* d_in, const int* in_sizes, int n_in,
                              void* d_out, int out_size, void* d_ws, size_t ws_size,
                              hipStream_t stream) {
    (void)in_sizes; (void)n_in; (void)out_size; (void)ws_size;
    const float* tok   = (const float*)d_in[0];
    const float* geo   = (const float*)d_in[1];
    const float* edge  = (const float*)d_in[2];
    const int*   nbr   = (const int*)d_in[3];
    const void*  maskp = d_in[5];
    const float* ln_qkv_g = (const float*)d_in[6];
    const float* ln_qkv_b = (const float*)d_in[7];
    const float* Wqkv  = (const float*)d_in[8];
    const float* bqkv  = (const float*)d_in[9];
    const float* ln_e_g = (const float*)d_in[10];
    const float* ln_e_b = (const float*)d_in[11];
    const float* Wqkve = (const float*)d_in[12];
    const float* bqkve = (const float*)d_in[13];
    const float* w_attn = (const float*)d_in[14];
    const float* w_edge = (const float*)d_in[15];
    const float* Wgate = (const float*)d_in[16];
    const float* bgate = (const float*)d_in[17];
    const float* Wfc1  = (const float*)d_in[18];
    const float* bfc1  = (const float*)d_in[19];
    const float* lnhg  = (const float*)d_in[20];
    const float* lnhb  = (const float*)d_in[21];
    const float* Wfc2  = (const float*)d_in[22];
    const float* bfc2  = (const float*)d_in[23];
    const float* Wfa   = (const float*)d_in[24];
    const float* bfa   = (const float*)d_in[25];
    float* ws  = (float*)d_ws;
    float* out = (float*)d_out;

    k_pre<<<dim3(38), dim3(256), 0, stream>>>(Wqkv, bqkv, Wqkve, bqkve, w_attn, w_edge,
                                              ln_e_g, ln_e_b, (const int*)maskp, geo, ws);
    k_tokprep<<<dim3(1024), dim3(256), 0, stream>>>(tok, ln_qkv_g, ln_qkv_b, Wgate, bgate,
                                                    Wqkv, bqkv, ws);
    k_attn<<<dim3(8192), dim3(256), 0, stream>>>(edge, nbr, maskp, ln_e_g, ln_e_b, bqkve,
                                                 Wqkve, Wfa, bfa, geo, ws, out);
    k_mlp<<<dim3(1024), dim3(256), 0, stream>>>(tok, Wfc1, bfc1, lnhg, lnhb, Wfc2, bfc2, ws, out);
}

// Round 5
// 392.172 us; speedup vs baseline: 1.0792x; 1.0141x over previous
//
#include <hip/hip_runtime.h>
#include <hip/hip_fp16.h>
#include <math.h>

#define NTOK 8192
#define NPG  512
#define MNEI 32
#define DM   256
#define DE   128
#define NH   8

// workspace offsets (in floats)
#define OFF_WQAK  65536u      // 16*256   [c][k] qa/ka transposed
#define OFF_BCAT  69632u      // 16 (cols 0..7 qa bias + edge-LN const fold, 8..15 ka bias)
#define OFF_WEF   69904u      // 8*128  [h][r]  wg = wef * ln_e_g  (LN gain folded)
#define OFF_FLAG  70936u      // 1 int
#define OFF_QA    70944u      // 8192*8
#define OFF_KA    136480u     // 8192*8
#define OFF_GATE  202016u     // 8192
#define OFF_VW    210208u     // 8192*256
#define OFF_PROJ  2307360u    // 8192*3
#define OFF_VMAT  2331936u    // 16*9
#define OFF_CEN   2332080u    // 16*3
#define OFF_HCAT  2332128u    // 8192*384

#define OUT_GEO_OFF 2097152   // 8192*256

__device__ __forceinline__ void fma4x4(const float4 a, const float4 w, float4* acc) {
    acc[0].x += a.x*w.x; acc[0].y += a.x*w.y; acc[0].z += a.x*w.z; acc[0].w += a.x*w.w;
    acc[1].x += a.y*w.x; acc[1].y += a.y*w.y; acc[1].z += a.y*w.z; acc[1].w += a.y*w.w;
    acc[2].x += a.z*w.x; acc[2].y += a.z*w.y; acc[2].z += a.z*w.z; acc[2].w += a.z*w.w;
    acc[3].x += a.w*w.x; acc[3].y += a.w*w.y; acc[3].z += a.w*w.z; acc[3].w += a.w*w.w;
}

__device__ __forceinline__ float dot4(const float4 a, const float4 b) {
    return a.x*b.x + a.y*b.y + a.z*b.z + a.w*b.w;
}

// ---------------- Kernel 1: merged preprocessing --------------------------
__global__ __launch_bounds__(256) void k_pre(
    const float* __restrict__ Wqkv, const float* __restrict__ bqkv,
    const float* __restrict__ Wqkve, const float* __restrict__ bqkve,
    const float* __restrict__ w_attn, const float* __restrict__ w_edge,
    const float* __restrict__ lneg, const float* __restrict__ lneb,
    const int* __restrict__ maskp, const float* __restrict__ geo,
    float* __restrict__ ws)
{
    int t = threadIdx.x;
    int b = blockIdx.x;

    if (b == 0) {
        __shared__ int sbad, sflt;
        if (t == 0) { sbad = 0; sflt = 0; }
        __syncthreads();
        int bad = 0, flt = 0;
        for (int i = 0; i < 256; i++) {
            unsigned int w = (unsigned int)maskp[i*256 + t];
            if (w > 1u) bad = 1;
            if (w == 0x3F800000u) flt = 1;
        }
        if (bad) atomicOr(&sbad, 1);
        if (flt) atomicOr(&sflt, 1);
        __syncthreads();
        if (t == 0) {
            int f = sflt ? 2 : (sbad ? 1 : 0);
            ((int*)(ws + OFF_FLAG))[0] = f;
        }
        return;
    }
    if (b == 1) {
        int h = t >> 5, l = t & 31;
        float p = 0.f;
        for (int q = 0; q < 4; q++) {
            int r = l + 32*q;
            float wef = 0.f;
            for (int e = 0; e < 16; e++) wef += Wqkve[r*256 + h*16 + e] * w_edge[e];
            p += lneb[r] * wef;
        }
        for (int m = 16; m >= 1; m >>= 1) p += __shfl_xor(p, m, 32);
        if (l == 0) {
            float s = p;
            for (int d = 0; d < 32; d++) s += bqkv[h*32 + d] * w_attn[d];
            for (int e = 0; e < 16; e++) s += bqkve[h*16 + e] * w_edge[e];
            ws[OFF_BCAT + h] = s;
        }
        if (l == 1) {
            float s = 0.f;
            for (int d = 0; d < 32; d++) s += bqkv[256 + h*32 + d] * w_attn[d];
            ws[OFF_BCAT + 8 + h] = s;
        }
        return;
    }
    if (b < 18) {
        int c = b - 2, k = t;
        int h = c & 7; int off = (c < 8) ? 0 : 256;
        float s = 0.f;
        for (int d = 0; d < 32; d++) s += Wqkv[k*768 + off + h*32 + d] * w_attn[d];
        ws[OFF_WQAK + c*256 + k] = s;
        return;
    }
    if (b < 22) {
        int i = (b - 18)*256 + t;
        int h = i >> 7, r = i & 127;
        float s = 0.f;
        for (int e = 0; e < 16; e++) s += Wqkve[r*256 + h*16 + e] * w_edge[e];
        ws[OFF_WEF + i] = s * lneg[r];
        return;
    }

    // ---- per-graph geometry: g = b - 22 ----
    {
        __shared__ float sred[4 * 9];
        __shared__ float sres[9];
        __shared__ float sV[9];
        int g = b - 22;
        int wave = t >> 6, lane = t & 63;
        const float* gp = geo + (size_t)g * NPG * 3;

        float x0[2], y0[2], z0[2];
        float sx = 0.f, sy = 0.f, sz = 0.f;
        for (int i = 0; i < 2; i++) {
            int p = t + 256 * i;
            x0[i] = gp[p*3 + 0]; y0[i] = gp[p*3 + 1]; z0[i] = gp[p*3 + 2];
            sx += x0[i]; sy += y0[i]; sz += z0[i];
        }
        {
            float vals[3] = {sx, sy, sz};
            for (int q = 0; q < 3; q++) {
                float v = vals[q];
                for (int m = 32; m >= 1; m >>= 1) v += __shfl_xor(v, m, 64);
                if (lane == 0) sred[wave*9 + q] = v;
            }
        }
        __syncthreads();
        if (t < 3) {
            float s = 0.f;
            for (int w = 0; w < 4; w++) s += sred[w*9 + t];
            sres[t] = s * (1.0f / 512.0f);
        }
        __syncthreads();
        float cx = sres[0], cy = sres[1], cz = sres[2];

        float c6[6] = {0.f, 0.f, 0.f, 0.f, 0.f, 0.f};
        for (int i = 0; i < 2; i++) {
            float dx = x0[i] - cx, dy = y0[i] - cy, dz = z0[i] - cz;
            c6[0] += dx*dx; c6[1] += dx*dy; c6[2] += dx*dz;
            c6[3] += dy*dy; c6[4] += dy*dz; c6[5] += dz*dz;
        }
        for (int q = 0; q < 6; q++) {
            float v = c6[q];
            for (int m = 32; m >= 1; m >>= 1) v += __shfl_xor(v, m, 64);
            if (lane == 0) sred[wave*9 + q] = v;
        }
        __syncthreads();
        if (t < 6) {
            float s = 0.f;
            for (int w = 0; w < 4; w++) s += sred[w*9 + t];
            sres[t] = s;
        }
        __syncthreads();

        if (t == 0) {
            double a[3][3];
            a[0][0] = sres[0]; a[0][1] = a[1][0] = sres[1]; a[0][2] = a[2][0] = sres[2];
            a[1][1] = sres[3]; a[1][2] = a[2][1] = sres[4]; a[2][2] = sres[5];
            double v[3][3] = {{1,0,0},{0,1,0},{0,0,1}};
            const int ps[3] = {0, 0, 1}, qs[3] = {1, 2, 2};
            for (int sweep = 0; sweep < 10; sweep++) {
                for (int pi = 0; pi < 3; pi++) {
                    int p = ps[pi], q = qs[pi];
                    double apq = a[p][q];
                    if (fabs(apq) < 1e-300) continue;
                    double theta = (a[q][q] - a[p][p]) / (2.0 * apq);
                    double tt = ((theta >= 0.0) ? 1.0 : -1.0) / (fabs(theta) + sqrt(theta*theta + 1.0));
                    double c = 1.0 / sqrt(tt*tt + 1.0), s = tt * c;
                    int k = 3 - p - q;
                    double app = a[p][p], aqq = a[q][q], akp = a[k][p], akq = a[k][q];
                    a[p][p] = app - tt * apq;
                    a[q][q] = aqq + tt * apq;
                    a[p][q] = 0.0; a[q][p] = 0.0;
                    a[k][p] = c*akp - s*akq; a[p][k] = a[k][p];
                    a[k][q] = s*akp + c*akq; a[q][k] = a[k][q];
                    for (int kk = 0; kk < 3; kk++) {
                        double vp = v[kk][p], vq = v[kk][q];
                        v[kk][p] = c*vp - s*vq;
                        v[kk][q] = s*vp + c*vq;
                    }
                }
            }
            for (int r = 0; r < 3; r++)
                for (int c2 = 0; c2 < 3; c2++) {
                    float fv = (float)v[r][c2];
                    sV[r*3 + c2] = fv;
                    ws[OFF_VMAT + g*9 + r*3 + c2] = fv;
                }
            ws[OFF_CEN + g*3 + 0] = cx;
            ws[OFF_CEN + g*3 + 1] = cy;
            ws[OFF_CEN + g*3 + 2] = cz;
        }
        __syncthreads();

        for (int i = 0; i < 2; i++) {
            int p = t + 256 * i;
            float dx = x0[i] - cx, dy = y0[i] - cy, dz = z0[i] - cz;
            for (int c = 0; c < 3; c++) {
                float pr = dx * sV[0*3 + c] + dy * sV[1*3 + c] + dz * sV[2*3 + c];
                ws[OFF_PROJ + (size_t)(g*NPG + p)*3 + c] = pr;
            }
        }
    }
}

// ---------------- Kernel 2: token LN + gate + [qa|ka|v] ---------------------
__global__ __launch_bounds__(256) void k_tokprep(
    const float* __restrict__ tok, const float* __restrict__ ln_g,
    const float* __restrict__ ln_b, const float* __restrict__ Wgate,
    const float* __restrict__ bgate, const float* __restrict__ Wqkv,
    const float* __restrict__ bqkv, float* __restrict__ ws)
{
    __shared__ __align__(16) float sln[256 * 12];   // [k][8 tokens + pad]
    int t = threadIdx.x;
    int tok0 = blockIdx.x * 8;

    #pragma unroll
    for (int q = 0; q < 8; q++)
        sln[t*12 + q] = tok[(size_t)(tok0 + q) * 256 + t];
    __syncthreads();

    int wave = t >> 6, lane = t & 63;
    for (int rr = 0; rr < 2; rr++) {
        int tt = wave * 2 + rr;
        float s = 0.f, gdot = 0.f;
        float xs[4];
        #pragma unroll
        for (int q = 0; q < 4; q++) {
            int k = lane + 64*q;
            float x = sln[k*12 + tt];
            xs[q] = x; s += x; gdot += x * Wgate[k];
        }
        for (int m = 32; m >= 1; m >>= 1) { s += __shfl_xor(s,m,64); gdot += __shfl_xor(gdot,m,64); }
        float mu = s * (1.0f/256.0f);
        float vs = 0.f;
        #pragma unroll
        for (int q = 0; q < 4; q++) { float d = xs[q]-mu; vs += d*d; }
        for (int m = 32; m >= 1; m >>= 1) vs += __shfl_xor(vs,m,64);
        float rinv = rsqrtf(vs*(1.0f/256.0f)+1e-5f);
        #pragma unroll
        for (int q = 0; q < 4; q++) {
            int k = lane + 64*q;
            sln[k*12 + tt] = (xs[q]-mu)*rinv*ln_g[k] + ln_b[k];
        }
        if (lane == 0) ws[OFF_GATE + tok0 + tt] = 1.0f/(1.0f+expf(-(gdot + bgate[0])));
    }
    __syncthreads();

    // ---- v-GEMM: all waves; thread (i = t>>6 -> tokens 2i,2i+1; j = t&63) ----
    {
        int i = t >> 6, j = t & 63;
        const float* Wc = Wqkv + 512 + 4*j;
        float4 acc0 = make_float4(0.f,0.f,0.f,0.f);
        float4 acc1 = make_float4(0.f,0.f,0.f,0.f);
        #pragma unroll 8
        for (int k = 0; k < 256; k++) {
            float a0 = sln[k*12 + 2*i];
            float a1 = sln[k*12 + 2*i + 1];
            float4 w4 = *(const float4*)&Wc[(size_t)k*768];
            acc0.x += a0*w4.x; acc0.y += a0*w4.y; acc0.z += a0*w4.z; acc0.w += a0*w4.w;
            acc1.x += a1*w4.x; acc1.y += a1*w4.y; acc1.z += a1*w4.z; acc1.w += a1*w4.w;
        }
        float4 b4 = *(const float4*)&bqkv[512 + 4*j];
        int n0 = tok0 + 2*i;
        acc0.x += b4.x; acc0.y += b4.y; acc0.z += b4.z; acc0.w += b4.w;
        acc1.x += b4.x; acc1.y += b4.y; acc1.z += b4.z; acc1.w += b4.w;
        *(float4*)&ws[OFF_VW + (size_t)n0*256 + 4*j]     = acc0;
        *(float4*)&ws[OFF_VW + (size_t)(n0+1)*256 + 4*j] = acc1;
    }

    // ---- qa/ka: t<128 (col = t&15, token tp = t>>4) ----
    if (t < 128) {
        int col = t & 15, tp = t >> 4;
        const float* wq = ws + OFF_WQAK + col*256;
        float acc = 0.f;
        #pragma unroll 8
        for (int k4 = 0; k4 < 64; k4++) {
            float4 w4 = *(const float4*)&wq[4*k4];
            acc += w4.x * sln[(4*k4+0)*12 + tp]
                 + w4.y * sln[(4*k4+1)*12 + tp]
                 + w4.z * sln[(4*k4+2)*12 + tp]
                 + w4.w * sln[(4*k4+3)*12 + tp];
        }
        acc += ws[OFF_BCAT + col];
        int n = tok0 + tp;
        if (col < 8) ws[OFF_QA + n*8 + col] = acc;
        else         ws[OFF_KA + n*8 + (col - 8)] = acc;
    }
}

// ---------------- Kernel 3: fused per-token attention (LN-folded) ----------
// v5: centered edge rows stored fp16 (seh, 32x136 half = 8.7KB) -> LDS
// 14.4KB -> 8 blocks/CU (32 waves, full occupancy). Logits stay fp32 (from
// registers, before conversion). P3 waves2-3 remapped: thread = (h, col-octet),
// unpacks 8 halfs/row. Load placement reverted to R2 (loads AFTER bar1 so
// they overlap P1 compute instead of draining into bar1's vmcnt(0)).
// sec (P4 reduce) aliases seh. 5 barriers.
__global__ __launch_bounds__(256, 8) void k_attn(
    const float* __restrict__ edge, const int* __restrict__ nbr,
    const void* __restrict__ maskp,
    const float* __restrict__ lneg, const float* __restrict__ lneb,
    const float* __restrict__ bqkve, const float* __restrict__ Wqkve,
    const float* __restrict__ Wfa, const float* __restrict__ bfa,
    const float* __restrict__ geo, float* __restrict__ ws, float* __restrict__ out)
{
    __shared__ __align__(16) unsigned short seh[32 * 136]; // fp16 centered rows; sec aliases in P4
    __shared__ __align__(16) float uSWE[8 * 132];   // [sub][h][16] wg; sew aliases after logits
    __shared__ __align__(16) float sattn[8 * 36];   // logits -> attn (in place)
    __shared__ float srinv[32];
    __shared__ int   snbr[32];
    __shared__ float sg3[4];

    int t = threadIdx.x;
    int n = blockIdx.x;
    int g = n >> 9;
    int flag = ((const int*)(ws + OFF_FLAG))[0];

    int m = t >> 3, sub = t & 7;

    // ---- P0: direct global->reg row load + small staging ----
    const float4* xp = (const float4*)(edge + (size_t)n * 4096 + m*128 + sub*16);
    float4 x0 = xp[0], x1 = xp[1], x2 = xp[2], x3 = xp[3];
    {
        // wg weights re-laid out sub-major: uSWE[s2*132 + h*16 + c]
        int idx = t * 4;
        int h = idx >> 7, r = idx & 127;
        int s2 = r >> 4, c = r & 15;
        *(float4*)&uSWE[s2*132 + h*16 + c] = *(const float4*)&ws[OFF_WEF + idx];
    }
    if (t < 32) snbr[t] = nbr[n*32 + t];
    __syncthreads();   // bar1

    // ---- P1: row stats + fp16 centered-row LDS write + logits (fp32 regs) ----
    {
        float s = x0.x+x0.y+x0.z+x0.w + x1.x+x1.y+x1.z+x1.w
                + x2.x+x2.y+x2.z+x2.w + x3.x+x3.y+x3.z+x3.w;
        for (int mm = 4; mm >= 1; mm >>= 1) s += __shfl_xor(s, mm, 8);
        float mu = s * (1.0f / 128.0f);
        x0.x-=mu; x0.y-=mu; x0.z-=mu; x0.w-=mu;
        x1.x-=mu; x1.y-=mu; x1.z-=mu; x1.w-=mu;
        x2.x-=mu; x2.y-=mu; x2.z-=mu; x2.w-=mu;
        x3.x-=mu; x3.y-=mu; x3.z-=mu; x3.w-=mu;
        float vs = dot4(x0,x0) + dot4(x1,x1) + dot4(x2,x2) + dot4(x3,x3);
        for (int mm = 4; mm >= 1; mm >>= 1) vs += __shfl_xor(vs, mm, 8);
        float rinv = rsqrtf(vs * (1.0f / 128.0f) + 1e-5f);

        // fp16 pack (RTN) + two 16B stores
        unsigned int u[8];
        {
            __half2 hh;
            hh = __floats2half2_rn(x0.x, x0.y); u[0] = *(unsigned int*)&hh;
            hh = __floats2half2_rn(x0.z, x0.w); u[1] = *(unsigned int*)&hh;
            hh = __floats2half2_rn(x1.x, x1.y); u[2] = *(unsigned int*)&hh;
            hh = __floats2half2_rn(x1.z, x1.w); u[3] = *(unsigned int*)&hh;
            hh = __floats2half2_rn(x2.x, x2.y); u[4] = *(unsigned int*)&hh;
            hh = __floats2half2_rn(x2.z, x2.w); u[5] = *(unsigned int*)&hh;
            hh = __floats2half2_rn(x3.x, x3.y); u[6] = *(unsigned int*)&hh;
            hh = __floats2half2_rn(x3.z, x3.w); u[7] = *(unsigned int*)&hh;
        }
        uint4* sp = (uint4*)&seh[m*136 + sub*16];
        sp[0] = make_uint4(u[0], u[1], u[2], u[3]);
        sp[1] = make_uint4(u[4], u[5], u[6], u[7]);
        if (sub == 0) srinv[m] = rinv;

        // logits: dot(wg[h], x - mu) for all h, butterfly over 8 sub-lanes
        float accl[8];
        const float* wb = &uSWE[sub*132];
        #pragma unroll
        for (int h = 0; h < 8; h++) {
            const float4* wp = (const float4*)(wb + h*16);
            accl[h] = dot4(x0,wp[0]) + dot4(x1,wp[1]) + dot4(x2,wp[2]) + dot4(x3,wp[3]);
        }
        #pragma unroll
        for (int st = 1; st < 8; st <<= 1) {
            #pragma unroll
            for (int h = 0; h < 8; h++) accl[h] += __shfl_xor(accl[h], st, 8);
        }
        float myacc = accl[0];
        #pragma unroll
        for (int h = 1; h < 8; h++) myacc = (sub == h) ? accl[h] : myacc;

        int mv;
        if (flag == 1)      mv = (int)((const unsigned char*)maskp)[n*32 + m];
        else if (flag == 2) mv = (((const float*)maskp)[n*32 + m] != 0.0f) ? 1 : 0;
        else                mv = ((const int*)maskp)[n*32 + m];

        float lg = myacc * rinv
                 + ws[OFF_QA + n*8 + sub]
                 + ws[OFF_KA + (size_t)snbr[m]*8 + sub];
        if (!mv) lg = -1e9f;
        sattn[sub*36 + m] = lg;
    }
    __syncthreads();   // bar2

    // ---- P2: softmax over m per h (in place) ----
    {
        int h = t >> 5, m2 = t & 31;
        float x = sattn[h*36 + m2];
        float mx = x;
        for (int mm = 16; mm >= 1; mm >>= 1) mx = fmaxf(mx, __shfl_xor(mx, mm, 32));
        float e = expf(x - mx);
        float sum = e;
        for (int mm = 16; mm >= 1; mm >>= 1) sum += __shfl_xor(sum, mm, 32);
        sattn[h*36 + m2] = e / sum;
    }
    __syncthreads();   // bar3 (uSWE dead -> sew aliases it)

    float* sew = uSWE;

    // ---- P3: wave-specialized: sctx gather | geo | weighted centered rows ----
    int wave = t >> 6;
    if (wave == 0) {
        int c4 = t, h = c4 >> 3;
        const float* vw = ws + OFF_VW;
        float4 acc = make_float4(0.f,0.f,0.f,0.f);
        #pragma unroll 4
        for (int mi = 0; mi < 32; mi++) {
            float a = sattn[h*36 + mi];
            int row = snbr[mi];
            float4 v4 = *(const float4*)&vw[(size_t)row*256 + 4*c4];
            acc.x += a*v4.x; acc.y += a*v4.y; acc.z += a*v4.z; acc.w += a*v4.w;
        }
        *(float4*)&ws[OFF_HCAT + (size_t)n*384 + 4*c4] = acc;
    } else if (wave == 1) {
        int lm = t - 64;
        if (lm < 32) {
            float wmv = 0.f;
            #pragma unroll
            for (int h2 = 0; h2 < 8; h2++) wmv += Wfa[h2] * sattn[h2*36 + lm];
            int row = snbr[lm];
            const float* pp = ws + OFF_PROJ + (size_t)row*3;
            float q0 = wmv * pp[0], q1 = wmv * pp[1], q2 = wmv * pp[2];
            for (int st = 16; st >= 1; st >>= 1) {
                q0 += __shfl_xor(q0, st, 32);
                q1 += __shfl_xor(q1, st, 32);
                q2 += __shfl_xor(q2, st, 32);
            }
            if (lm < 3) {
                float sd = (lm == 0) ? q0 : (lm == 1) ? q1 : q2;
                float bb = bfa[0];
                float p1 = sd + bb, p2 = -sd + bb;
                float s1v = p1 / (1.0f + expf(-p1));
                float s2v = p2 / (1.0f + expf(-p2));
                sg3[lm] = 0.5f * (s1v - s2v);
            }
        }
    } else {
        // thread = (h, col-octet): h = idx>>4, rh = idx&15 -> cols 8rh..8rh+7
        int idx = t - 128;
        int rh = idx & 15, h = idx >> 4;
        float4 fA = make_float4(0.f,0.f,0.f,0.f);
        float4 fB = make_float4(0.f,0.f,0.f,0.f);
        #pragma unroll 4
        for (int mi = 0; mi < 32; mi++) {
            float a = sattn[h*36 + mi] * srinv[mi];
            uint4 v = *(const uint4*)&seh[mi*136 + rh*8];
            float2 f0 = __half22float2(*(__half2*)&v.x);
            float2 f1 = __half22float2(*(__half2*)&v.y);
            float2 f2 = __half22float2(*(__half2*)&v.z);
            float2 f3 = __half22float2(*(__half2*)&v.w);
            fA.x += a*f0.x; fA.y += a*f0.y; fA.z += a*f1.x; fA.w += a*f1.y;
            fB.x += a*f2.x; fB.y += a*f2.y; fB.z += a*f3.x; fB.w += a*f3.y;
        }
        float4 g4a = *(const float4*)&lneg[8*rh];
        float4 g4b = *(const float4*)&lneg[8*rh + 4];
        float4 b4a = *(const float4*)&lneb[8*rh];
        float4 b4b = *(const float4*)&lneb[8*rh + 4];
        float4 o1, o2;
        o1.x = g4a.x*fA.x + b4a.x; o1.y = g4a.y*fA.y + b4a.y;
        o1.z = g4a.z*fA.z + b4a.z; o1.w = g4a.w*fA.w + b4a.w;
        o2.x = g4b.x*fB.x + b4b.x; o2.y = g4b.y*fB.y + b4b.y;
        o2.z = g4b.z*fB.z + b4b.z; o2.w = g4b.w*fB.w + b4b.w;
        *(float4*)&sew[h*132 + 8*rh]     = o1;
        *(float4*)&sew[h*132 + 8*rh + 4] = o2;
    }
    __syncthreads();   // bar4 (seh dead; sec aliases it)

    // ---- P4: edge ctx GEMM (coalesced float4, K-split 8 row-groups) ----
    float* sec = (float*)seh;
    {
        int col4 = t & 31, rgrp = t >> 5;
        int h2 = col4 >> 2;
        const float* wqb = Wqkve + 128 + 4*col4;
        float4 accE = make_float4(0.f,0.f,0.f,0.f);
        #pragma unroll 4
        for (int ri = 0; ri < 16; ri++) {
            int r = rgrp*16 + ri;
            float sv = sew[h2*132 + r];
            float4 w4 = *(const float4*)&wqb[(size_t)r*256];
            accE.x += sv*w4.x; accE.y += sv*w4.y; accE.z += sv*w4.z; accE.w += sv*w4.w;
        }
        *(float4*)&sec[rgrp*128 + 4*col4] = accE;
    }
    __syncthreads();   // bar5

    if (t < 128) {
        float ec = bqkve[128 + t];
        #pragma unroll
        for (int g2 = 0; g2 < 8; g2++) ec += sec[g2*128 + t];
        ws[OFF_HCAT + (size_t)n*384 + 256 + t] = ec;
    }
    if (t < 3) {
        const float* Vm = ws + OFF_VMAT + g*9;
        float gc = Vm[t*3+0]*sg3[0] + Vm[t*3+1]*sg3[1] + Vm[t*3+2]*sg3[2] + ws[OFF_CEN + g*3 + t];
        float gt = ws[OFF_GATE + n];
        out[OUT_GEO_OFF + (size_t)n*3 + t] = gc * gt + geo[(size_t)n*3 + t] * (1.0f - gt);
    }
}

// ---------------- Kernel 4: MLP — 8 tokens/block, K-split halves -----------
__global__ __launch_bounds__(256) void k_mlp(
    const float* __restrict__ tok, const float* __restrict__ Wfc1,
    const float* __restrict__ bfc1, const float* __restrict__ lnhg,
    const float* __restrict__ lnhb, const float* __restrict__ Wfc2,
    const float* __restrict__ bfc2, const float* __restrict__ ws,
    float* __restrict__ out)
{
    __shared__ __align__(16) float A[384 * 12];   // [k][8 tokens + pad]
    __shared__ __align__(16) float R[128 * 16];   // cross-half reduce
    int t = threadIdx.x;
    int tok0 = blockIdx.x * 8;
    int i2 = (t >> 6) & 1, kh = t >> 7, j = t & 63;
    const float* hc = ws + OFF_HCAT;

    #pragma unroll
    for (int q = 0; q < 12; q++) {
        int idx = q*256 + t;
        int tt = idx / 384;
        int k  = idx - tt*384;
        A[k*12 + tt] = hc[(size_t)tok0*384 + idx];
    }
    __syncthreads();

    // fc1 (half K per thread)
    float4 acc1[4];
    acc1[0] = acc1[1] = acc1[2] = acc1[3] = make_float4(0.f,0.f,0.f,0.f);
    {
        const float* wp = Wfc1 + 4*j;
        int kbase = kh * 192;
        #pragma unroll 8
        for (int kk = 0; kk < 192; kk++) {
            int k = kbase + kk;
            float4 a4 = *(const float4*)&A[k*12 + 4*i2];
            float4 w4 = *(const float4*)&wp[(size_t)k*256];
            fma4x4(a4, w4, acc1);
        }
    }
    if (kh == 1) {
        int rowid = t - 128;
        #pragma unroll
        for (int ti = 0; ti < 4; ti++) *(float4*)&R[rowid*16 + ti*4] = acc1[ti];
    }
    __syncthreads();

    float h[4][4];
    if (kh == 0) {
        float4 b4 = *(const float4*)&bfc1[4*j];
        #pragma unroll
        for (int ti = 0; ti < 4; ti++) {
            float4 p = *(const float4*)&R[t*16 + ti*4];
            float xv[4] = {acc1[ti].x + p.x + b4.x, acc1[ti].y + p.y + b4.y,
                           acc1[ti].z + p.z + b4.z, acc1[ti].w + p.w + b4.w};
            #pragma unroll
            for (int c = 0; c < 4; c++) {
                float x = xv[c];
                h[ti][c] = 0.5f * x * (1.0f + erff(x * 0.70710678118654752f));
            }
        }
        // LN across the 64 j-lanes (wave i2 shares tokens 4i2..4i2+3)
        float s[4], qv[4];
        #pragma unroll
        for (int ti = 0; ti < 4; ti++) {
            s[ti]  = h[ti][0] + h[ti][1] + h[ti][2] + h[ti][3];
            qv[ti] = h[ti][0]*h[ti][0] + h[ti][1]*h[ti][1] + h[ti][2]*h[ti][2] + h[ti][3]*h[ti][3];
        }
        for (int m = 32; m >= 1; m >>= 1)
            #pragma unroll
            for (int ti = 0; ti < 4; ti++) {
                s[ti]  += __shfl_xor(s[ti], m, 64);
                qv[ti] += __shfl_xor(qv[ti], m, 64);
            }
        float4 g4 = *(const float4*)&lnhg[4*j];
        float4 b42 = *(const float4*)&lnhb[4*j];
        float gg[4] = {g4.x, g4.y, g4.z, g4.w};
        float bb[4] = {b42.x, b42.y, b42.z, b42.w};
        #pragma unroll
        for (int ti = 0; ti < 4; ti++) {
            float mu = s[ti] * (1.0f/256.0f);
            float var = qv[ti] * (1.0f/256.0f) - mu*mu;
            float rinv = rsqrtf(var + 1e-5f);
            #pragma unroll
            for (int c = 0; c < 4; c++) {
                float hn = (h[ti][c] - mu) * rinv * gg[c] + bb[c];
                A[(4*j + c)*12 + 4*i2 + ti] = hn;
            }
        }
    }
    __syncthreads();

    // fc2 (half K per thread)
    float4 acc2[4];
    acc2[0] = acc2[1] = acc2[2] = acc2[3] = make_float4(0.f,0.f,0.f,0.f);
    {
        const float* wp = Wfc2 + 4*j;
        int kbase = kh * 128;
        #pragma unroll 8
        for (int kk = 0; kk < 128; kk++) {
            int k = kbase + kk;
            float4 a4 = *(const float4*)&A[k*12 + 4*i2];
            float4 w4 = *(const float4*)&wp[(size_t)k*256];
            fma4x4(a4, w4, acc2);
        }
    }
    if (kh == 1) {
        int rowid = t - 128;
        #pragma unroll
        for (int ti = 0; ti < 4; ti++) *(float4*)&R[rowid*16 + ti*4] = acc2[ti];
    }
    __syncthreads();

    if (kh == 0) {
        float4 b4 = *(const float4*)&bfc2[4*j];
        #pragma unroll
        for (int ti = 0; ti < 4; ti++) {
            float4 p = *(const float4*)&R[t*16 + ti*4];
            size_t o = (size_t)(tok0 + 4*i2 + ti) * 256 + 4*j;
            float4 r4 = *(const float4*)&tok[o];
            float4 v;
            v.x = acc2[ti].x + p.x + b4.x + r4.x;
            v.y = acc2[ti].y + p.y + b4.y + r4.y;
            v.z = acc2[ti].z + p.z + b4.z + r4.z;
            v.w = acc2[ti].w + p.w + b4.w + r4.w;
            *(float4*)&out[o] = v;
        }
    }
}

extern "C" void kernel_launch(void* const* d_in, const int* in_sizes, int n_in,
                              void* d_out, int out_size, void* d_ws, size_t ws_size,
                              hipStream_t stream) {
    (void)in_sizes; (void)n_in; (void)out_size; (void)ws_size;
    const float* tok   = (const float*)d_in[0];
    const float* geo   = (const float*)d_in[1];
    const float* edge  = (const float*)d_in[2];
    const int*   nbr   = (const int*)d_in[3];
    const void*  maskp = d_in[5];
    const float* ln_qkv_g = (const float*)d_in[6];
    const float* ln_qkv_b = (const float*)d_in[7];
    const float* Wqkv  = (const float*)d_in[8];
    const float* bqkv  = (const float*)d_in[9];
    const float* ln_e_g = (const float*)d_in[10];
    const float* ln_e_b = (const float*)d_in[11];
    const float* Wqkve = (const float*)d_in[12];
    const float* bqkve = (const float*)d_in[13];
    const float* w_attn = (const float*)d_in[14];
    const float* w_edge = (const float*)d_in[15];
    const float* Wgate = (const float*)d_in[16];
    const float* bgate = (const float*)d_in[17];
    const float* Wfc1  = (const float*)d_in[18];
    const float* bfc1  = (const float*)d_in[19];
    const float* lnhg  = (const float*)d_in[20];
    const float* lnhb  = (const float*)d_in[21];
    const float* Wfc2  = (const float*)d_in[22];
    const float* bfc2  = (const float*)d_in[23];
    const float* Wfa   = (const float*)d_in[24];
    const float* bfa   = (const float*)d_in[25];
    float* ws  = (float*)d_ws;
    float* out = (float*)d_out;

    k_pre<<<dim3(38), dim3(256), 0, stream>>>(Wqkv, bqkv, Wqkve, bqkve, w_attn, w_edge,
                                              ln_e_g, ln_e_b, (const int*)maskp, geo, ws);
    k_tokprep<<<dim3(1024), dim3(256), 0, stream>>>(tok, ln_qkv_g, ln_qkv_b, Wgate, bgate,
                                                    Wqkv, bqkv, ws);
    k_attn<<<dim3(8192), dim3(256), 0, stream>>>(edge, nbr, maskp, ln_e_g, ln_e_b, bqkve,
                                                 Wqkve, Wfa, bfa, geo, ws, out);
    k_mlp<<<dim3(1024), dim3(256), 0, stream>>>(tok, Wfc1, bfc1, lnhg, lnhb, Wfc2, bfc2, ws, out);
}